// Round 4
// baseline (779.697 us; speedup 1.0000x reference)
//
#include <hip/hip_runtime.h>
#include <cstdint>

// Problem constants
#define M_TOK 32768   // B*S
#define BERT  768
#define HID   512
#define LAT   128
#define NV    4096
#define NK    100
#define VOCAB 30522
#define NB    128     // batch B

typedef short short8 __attribute__((ext_vector_type(8)));
typedef float floatx4 __attribute__((ext_vector_type(4)));
typedef unsigned short u16x4 __attribute__((ext_vector_type(4)));
typedef unsigned short u16x8 __attribute__((ext_vector_type(8)));

// ---- truncation split: v == h+m+l EXACTLY (24-bit mantissa = 8+8+8) -------
__device__ __forceinline__ void tsplit3(float v, unsigned short& h,
                                        unsigned short& m, unsigned short& l) {
    unsigned u = __float_as_uint(v);
    h = (unsigned short)(u >> 16);
    float r = v - __uint_as_float(u & 0xFFFF0000u);
    unsigned ur = __float_as_uint(r);
    m = (unsigned short)(ur >> 16);
    float r2 = r - __uint_as_float(ur & 0xFFFF0000u);
    l = (unsigned short)(__float_as_uint(r2) >> 16);
}

// ---- async global->LDS, 16B per lane --------------------------------------
__device__ __forceinline__ void async16(const void* g, void* l) {
    __builtin_amdgcn_global_load_lds(
        (const __attribute__((address_space(1))) unsigned int*)g,
        (__attribute__((address_space(3))) unsigned int*)l, 16, 0, 0);
}

// ---------------------------------------------------------------------------
// Weight split+transpose: W[K][N] f32 -> Wt limbs [3][N][K] bf16 (truncated).
// 64x64 LDS tile transpose: coalesced reads AND ~128B-chunk writes.
// Requires K%64==0, N%64==0 (true for all 4 weights).
// ---------------------------------------------------------------------------
__global__ __launch_bounds__(256) void wsplit(
    const float* __restrict__ W, unsigned short* __restrict__ Wt,
    int K, int N)
{
    __shared__ unsigned short T[3][64][72];   // [limb][n][k], padded to 72
    int tk = blockIdx.x * 64;
    int tn = blockIdx.y * 64;
    int t = threadIdx.x;
    int lc = t & 63;          // n within tile
    int lr0 = t >> 6;         // 0..3
#pragma unroll
    for (int i = 0; i < 16; ++i) {
        int r = lr0 + i * 4;  // k within tile
        float v = W[(size_t)(tk + r) * N + tn + lc];
        unsigned short h, m, l;
        tsplit3(v, h, m, l);
        T[0][lc][r] = h;
        T[1][lc][r] = m;
        T[2][lc][r] = l;
    }
    __syncthreads();
    int n = t >> 2;               // 0..63
    int kq = (t & 3) * 16;        // 0,16,32,48
    size_t NKt = (size_t)N * K;
#pragma unroll
    for (int l = 0; l < 3; ++l) {
        unsigned short* dst = Wt + (size_t)l * NKt + (size_t)(tn + n) * K + tk + kq;
        u16x8 v0 = *(const u16x8*)&T[l][n][kq];
        u16x8 v1 = *(const u16x8*)&T[l][n][kq + 8];
        *(u16x8*)dst = v0;
        *(u16x8*)(dst + 8) = v1;
    }
}

// ---------------------------------------------------------------------------
// Multi-limb bf16 MFMA GEMM with double-buffered B staging.
// C[M,N] = A(f32)[M,K] @ W[K,N] + bias, opt ReLU. W pre-split as Wt[NL][N][K].
// Products with al+bl < NL: NL=3 -> 6 (f32-exact inputs), NL=2 -> 3.
// 128x128 tile, BK=32, 256 thr (4 waves, each 64x64 via 4x4 of 16x16x32).
// Staging loads for tile k+1 are issued at the TOP of the MFMA phase of tile
// k, so the barrier that drains vmcnt sits ~1800 MFMA-cycles later (hides
// global->LDS latency; the R3 structure exposed it every iteration).
// Requires M%128==0, N%128==0, K%64==0.
// ---------------------------------------------------------------------------
template<int NL, bool RELU>
__global__ __launch_bounds__(256) void gemm_mfma(
    const float* __restrict__ A, const unsigned short* __restrict__ Wt,
    const float* __restrict__ bias, float* __restrict__ C,
    int M, int N, int K)
{
    __shared__ unsigned short Ash[NL][4096];
    __shared__ unsigned short Bsh0[NL][4096];
    __shared__ unsigned short Bsh1[NL][4096];

    const int tid  = threadIdx.x;
    const int lane = tid & 63;
    const int wave = tid >> 6;
    const int bm = blockIdx.y * 128;
    const int bn = blockIdx.x * 128;
    const int wm = (wave & 1) * 64;
    const int wn = (wave >> 1) * 64;

    // A staging: 4 rows/thread (r = ar+32i), k-chunk ak..ak+3
    const int ar = tid >> 3;          // 0..31
    const int ak = (tid & 7) * 4;     // 0,4,..28
    // B staging (global_load_lds): per limb 2 issues; row br+64i, k-off bk
    const int br = tid >> 2;          // 0..63
    const int bk = (tid & 3) * 8;     // 0,8,16,24

    floatx4 acc[4][4];
#pragma unroll
    for (int t = 0; t < 4; ++t)
#pragma unroll
        for (int u = 0; u < 4; ++u)
            acc[t][u] = (floatx4)0.0f;

    float4 av[4];
    u16x4 ah[NL][4];

    auto split_av = [&]() {
#pragma unroll
        for (int i = 0; i < 4; ++i) {
            float vv[4] = {av[i].x, av[i].y, av[i].z, av[i].w};
#pragma unroll
            for (int e = 0; e < 4; ++e) {
                unsigned short h, m, l;
                tsplit3(vv[e], h, m, l);
                ah[0][i][e] = h;
                if (NL >= 2) ah[1][i][e] = m;
                if (NL >= 3) ah[2][i][e] = l;
            }
        }
    };
    auto write_A = [&]() {
#pragma unroll
        for (int l = 0; l < NL; ++l)
#pragma unroll
            for (int i = 0; i < 4; ++i)
                *(u16x4*)&Ash[l][(ar + 32 * i) * 32 + ak] = ah[l][i];
    };
    auto issue_B = [&](unsigned short (&Bn)[NL][4096], int k0) {
#pragma unroll
        for (int l = 0; l < NL; ++l) {
            const unsigned short* wp = Wt + (size_t)l * N * K;
#pragma unroll
            for (int i = 0; i < 2; ++i)
                async16(wp + (size_t)(bn + br + 64 * i) * K + k0 + bk,
                        &Bn[l][i * 2048 + tid * 8]);
        }
    };
    auto load_av = [&](int k0) {
#pragma unroll
        for (int i = 0; i < 4; ++i)
            av[i] = *(const float4*)(A + (size_t)(bm + ar + 32 * i) * K + k0 + ak);
    };

    // one K-step: MFMA on (Ash, Bc); prefetch k0+32 into (av regs, Bn)
    auto step = [&](int k0, unsigned short (&Bc)[NL][4096],
                    unsigned short (&Bn)[NL][4096]) {
        int kn = k0 + 32;
        bool has_nxt = kn < K;
        if (has_nxt) {
            issue_B(Bn, kn);      // completes under the MFMA phase below
            load_av(kn);
        }
        short8 af[NL][4];
#pragma unroll
        for (int l = 0; l < NL; ++l)
#pragma unroll
            for (int t = 0; t < 4; ++t)
                af[l][t] = *(const short8*)&Ash[l][(wm + t * 16 + (lane & 15)) * 32 + (lane >> 4) * 8];
#pragma unroll
        for (int bl = 0; bl < NL; ++bl) {
            short8 bf[4];
#pragma unroll
            for (int u = 0; u < 4; ++u)
                bf[u] = *(const short8*)&Bc[bl][(wn + u * 16 + (lane & 15)) * 32 + (lane >> 4) * 8];
#pragma unroll
            for (int al = 0; al < NL; ++al) {
                if (al + bl >= NL) continue;
#pragma unroll
                for (int t = 0; t < 4; ++t)
#pragma unroll
                    for (int u = 0; u < 4; ++u)
                        acc[t][u] = __builtin_amdgcn_mfma_f32_16x16x32_bf16(
                            af[al][t], bf[u], acc[t][u], 0, 0, 0);
            }
        }
        if (has_nxt) {
            split_av();
            __syncthreads();      // all waves done reading Ash; B(kn) long since landed
            write_A();
            __syncthreads();      // lgkm only — nothing pending on vmcnt
        }
    };

    // prologue: stage tile 0 (one exposed load latency per block)
    load_av(0);
    issue_B(Bsh0, 0);
    split_av();
    write_A();
    __syncthreads();

    for (int k0 = 0; k0 < K; k0 += 64) {
        step(k0,      Bsh0, Bsh1);
        step(k0 + 32, Bsh1, Bsh0);
    }

    // epilogue: D col=lane&15, row=(lane>>4)*4+reg  [m89/m91-verified]
#pragma unroll
    for (int t = 0; t < 4; ++t) {
        int row0 = bm + wm + t * 16 + (lane >> 4) * 4;
#pragma unroll
        for (int u = 0; u < 4; ++u) {
            int col = bn + wn + u * 16 + (lane & 15);
            float b = bias[col];
#pragma unroll
            for (int r = 0; r < 4; ++r) {
                float v = acc[t][u][r] + b;
                if (RELU) v = fmaxf(v, 0.f);
                C[(size_t)(row0 + r) * N + col] = v;
            }
        }
    }
}

// ---------------------------------------------------------------------------
// Row L2-normalize, rows of length 128. One wave (64 lanes) per row.
// ---------------------------------------------------------------------------
__global__ __launch_bounds__(64) void rownorm128(const float* __restrict__ in,
                                                 float* __restrict__ out)
{
    int row = blockIdx.x;
    int l = threadIdx.x;
    const float* p = in + (size_t)row * 128;
    float v0 = p[l], v1 = p[l + 64];
    float s = v0 * v0 + v1 * v1;
#pragma unroll
    for (int o = 32; o > 0; o >>= 1) s += __shfl_xor(s, o, 64);
    float inv = 1.0f / sqrtf(s);
    float* q = out + (size_t)row * 128;
    q[l] = v0 * inv;
    q[l + 64] = v1 * inv;
}

// ---------------------------------------------------------------------------
// Segment mean, phase 1: int histogram of ids (4096-way spread -> cheap).
// ---------------------------------------------------------------------------
__global__ __launch_bounds__(256) void bucket_count(
    const int* __restrict__ ids, int* __restrict__ freq_i)
{
    int t = blockIdx.x * 256 + threadIdx.x;
    atomicAdd(&freq_i[ids[t]], 1);
}

// phase 2: scatter token indices into fixed-capacity buckets (cap 64;
// P(binomial(32768,1/4096) >= 64) ~ e^-40 — unreachable).
__global__ __launch_bounds__(256) void bucket_fill(
    const int* __restrict__ ids, int* __restrict__ cursor,
    int* __restrict__ bucket)
{
    int t = blockIdx.x * 256 + threadIdx.x;
    int id = ids[t];
    int pos = atomicAdd(&cursor[id], 1);
    if (pos < 64) bucket[id * 64 + pos] = t;
}

// phase 3: one block per vocab id, coalesced direct sum (no f32 atomics).
__global__ __launch_bounds__(128) void avg_from_buckets(
    const float* __restrict__ z, const int* __restrict__ bucket,
    const int* __restrict__ freq_i, float* __restrict__ avg)
{
    int id = blockIdx.x;
    int t = threadIdx.x;
    int m = min(freq_i[id], 64);
    float s = 0.f;
    for (int j = 0; j < m; ++j)
        s += z[(size_t)bucket[id * 64 + j] * 128 + t];
    avg[(size_t)id * 128 + t] = s / (float)max(m, 1);
}

// ---------------------------------------------------------------------------
// argmax over logits = avg @ cn.T (softmax monotone -> same argmax).
// ---------------------------------------------------------------------------
__global__ __launch_bounds__(128) void argmax_kernel(
    const float* __restrict__ avg, const float* __restrict__ cn,
    int* __restrict__ cids, float* __restrict__ cids_f)
{
    __shared__ float arow[128];
    __shared__ float lg[NK];
    int row = blockIdx.x;
    int t = threadIdx.x;
    arow[t] = avg[(size_t)row * 128 + t];
    __syncthreads();
    if (t < NK) {
        float d = 0.f;
        const float* c = cn + (size_t)t * 128;
#pragma unroll 8
        for (int i = 0; i < 128; ++i) d += arow[i] * c[i];
        lg[t] = d;
    }
    __syncthreads();
    if (t == 0) {
        float best = lg[0];
        int bi = 0;
        for (int k = 1; k < NK; ++k) {
            if (lg[k] > best) { best = lg[k]; bi = k; }  // first-occurrence ties
        }
        cids[row] = bi;
        cids_f[row] = (float)bi;
    }
}

// ---------------------------------------------------------------------------
__global__ __launch_bounds__(256) void build_masks(
    const float* __restrict__ bow, unsigned long long* __restrict__ masks,
    float* __restrict__ cnt)
{
    int j = blockIdx.x * 256 + threadIdx.x;
    if (j >= NV) return;
    unsigned long long m0 = 0, m1 = 0;
    for (int b = 0; b < 64; ++b)
        if (bow[(size_t)b * VOCAB + j] != 0.f) m0 |= 1ull << b;
    for (int b = 0; b < 64; ++b)
        if (bow[(size_t)(b + 64) * VOCAB + j] != 0.f) m1 |= 1ull << b;
    masks[2 * j] = m0;
    masks[2 * j + 1] = m1;
    cnt[j] = (float)(__popcll(m0) + __popcll(m1));
}

// ---------------------------------------------------------------------------
__global__ __launch_bounds__(256) void co_kernel(
    const unsigned long long* __restrict__ masks, const float* __restrict__ cnt,
    float* __restrict__ co)
{
    int j = blockIdx.x * 256 + threadIdx.x;
    unsigned long long m0 = masks[2 * j], m1 = masks[2 * j + 1];
    float cj = cnt[j];
    int ibase = blockIdx.y * 64;
    for (int ii = 0; ii < 64; ++ii) {
        int i = ibase + ii;
        unsigned long long a0 = masks[2 * i], a1 = masks[2 * i + 1];
        float ci = cnt[i];
        float c = (float)(__popcll(a0 & m0) + __popcll(a1 & m1));
        co[(size_t)i * NV + j] = (float)NB * c / (ci * cj);
    }
}

// ---------------------------------------------------------------------------
// Closed-form cluster scan (see Round-1 derivation).
// ---------------------------------------------------------------------------
__global__ __launch_bounds__(128) void cluster_scan(
    const float* __restrict__ avg, const int* __restrict__ cids,
    const int* __restrict__ freq_i, const float* __restrict__ vw,
    const float* __restrict__ centers, const float* __restrict__ counts,
    float* __restrict__ out_centers)
{
    __shared__ int list[NV];
    __shared__ float coef[NV];
    __shared__ int tcnt[128];
    __shared__ int tot;
    __shared__ float Ptot;

    int k = blockIdx.x;
    int t = threadIdx.x;

    int base = t * (NV / 128);
    int c = 0;
    for (int s = 0; s < NV / 128; ++s) {
        int i = base + s;
        if (cids[i] == k && freq_i[i] > 0) c++;
    }
    tcnt[t] = c;
    __syncthreads();
    if (t == 0) {
        int run = 0;
        for (int x = 0; x < 128; ++x) { int v = tcnt[x]; tcnt[x] = run; run += v; }
        tot = run;
    }
    __syncthreads();
    int off = tcnt[t];
    for (int s = 0; s < NV / 128; ++s) {
        int i = base + s;
        if (cids[i] == k && freq_i[i] > 0) list[off++] = i;
    }
    __syncthreads();
    int m = tot;

    float c0 = counts[k];
    for (int j = t; j < m; j += 128)
        coef[j] = vw[list[j]] / (c0 + (float)(j + 1));
    __syncthreads();
    if (t == 0) {
        float suf = 1.f;
        for (int j = m - 1; j >= 0; --j) {
            float e = coef[j];
            coef[j] = e * suf;
            suf *= (1.f - e);
        }
        Ptot = suf;
    }
    __syncthreads();

    float accv = Ptot * centers[(size_t)k * 128 + t];
    for (int j = 0; j < m; ++j)
        accv += coef[j] * avg[(size_t)list[j] * 128 + t];
    out_centers[(size_t)k * 128 + t] = accv;
}

// ---------------------------------------------------------------------------
__global__ __launch_bounds__(64) void cn_norm(const float* __restrict__ centers,
                                              float* __restrict__ cn)
{
    int row = blockIdx.x;
    int l = threadIdx.x;
    const float* p = centers + (size_t)row * 128;
    float v0 = p[l], v1 = p[l + 64];
    float s = v0 * v0 + v1 * v1;
#pragma unroll
    for (int o = 32; o > 0; o >>= 1) s += __shfl_xor(s, o, 64);
    float inv = 1.0f / sqrtf(s);
    cn[(size_t)row * 128 + l] = v0 * inv;
    cn[(size_t)row * 128 + l + 64] = v1 * inv;
}

// ---------------------------------------------------------------------------
extern "C" void kernel_launch(void* const* d_in, const int* in_sizes, int n_in,
                              void* d_out, int out_size, void* d_ws, size_t ws_size,
                              hipStream_t stream)
{
    const int*   input_ids = (const int*)d_in[0];
    const float* token_embs = (const float*)d_in[3];
    const float* bow       = (const float*)d_in[4];
    const float* enc_w1    = (const float*)d_in[5];
    const float* enc_b1    = (const float*)d_in[6];
    const float* enc_w2    = (const float*)d_in[7];
    const float* enc_b2    = (const float*)d_in[8];
    const float* dec_w1    = (const float*)d_in[9];
    const float* dec_b1    = (const float*)d_in[10];
    const float* dec_w2    = (const float*)d_in[11];
    const float* dec_b2    = (const float*)d_in[12];
    const float* centers   = (const float*)d_in[13];
    const float* counts    = (const float*)d_in[14];
    const float* vocab_w   = (const float*)d_in[15];

    float* out = (float*)d_out;
    const size_t OFF_CO  = 0;                       // 4096*4096
    const size_t OFF_REC = 16777216;                // 32768*768
    const size_t OFF_AVG = OFF_REC + 25165824;      // 4096*128
    const size_t OFF_CID = OFF_AVG + 524288;        // 4096
    const size_t OFF_NC  = OFF_CID + 4096;          // 100*128

    // workspace layout
    float* h      = (float*)d_ws;                   // 32768*512 f32 (also hr)
    float* z      = h + (size_t)M_TOK * HID;        // 32768*128
    int*   freq_i = (int*)(z + (size_t)M_TOK * LAT);// 4096
    int*   cursor = freq_i + NV;                    // 4096
    int*   bucket = cursor + NV;                    // 4096*64
    float* cn     = (float*)(bucket + NV * 64);     // 100*128
    float* cntv   = cn + (size_t)NK * LAT;          // 4096
    int*   cids   = (int*)(cntv + NV);              // 4096
    unsigned long long* masks = (unsigned long long*)(cids + NV); // 4096*2
    unsigned short* wt1 = (unsigned short*)(masks + 2 * NV);      // 3*512*768
    unsigned short* wt2 = wt1 + (size_t)3 * HID * BERT;           // 3*128*512
    unsigned short* wt3 = wt2 + (size_t)3 * LAT * HID;            // 3*512*128
    unsigned short* wt4 = wt3 + (size_t)3 * HID * LAT;            // 3*768*512

    // zero the atomic targets (freq_i + cursor contiguous)
    hipMemsetAsync(freq_i, 0, 2 * NV * sizeof(int), stream);

    // weight split+transpose (bf16 truncated limbs, [N][K])
    wsplit<<<dim3(BERT / 64, HID / 64), 256, 0, stream>>>(enc_w1, wt1, BERT, HID);
    wsplit<<<dim3(HID / 64, LAT / 64), 256, 0, stream>>>(enc_w2, wt2, HID, LAT);
    wsplit<<<dim3(LAT / 64, HID / 64), 256, 0, stream>>>(dec_w1, wt3, LAT, HID);
    wsplit<<<dim3(HID / 64, BERT / 64), 256, 0, stream>>>(dec_w2, wt4, HID, BERT);

    // encoder (3-limb, 6 products: f32-exact inputs — protects argmax)
    gemm_mfma<3, true ><<<dim3(HID / 128, M_TOK / 128), 256, 0, stream>>>(
        token_embs, wt1, enc_b1, h, M_TOK, HID, BERT);
    gemm_mfma<3, false><<<dim3(LAT / 128, M_TOK / 128), 256, 0, stream>>>(
        h, wt2, enc_b2, z, M_TOK, LAT, HID);
    rownorm128<<<M_TOK, 64, 0, stream>>>(z, z);

    // decoder (2-limb, 3 products: rec only, generous threshold)
    gemm_mfma<2, true ><<<dim3(HID / 128, M_TOK / 128), 256, 0, stream>>>(
        z, wt3, dec_b1, h, M_TOK, HID, LAT);
    gemm_mfma<2, false><<<dim3(BERT / 128, M_TOK / 128), 256, 0, stream>>>(
        h, wt4, dec_b2, out + OFF_REC, M_TOK, BERT, HID);

    // segment mean — bucketed, no contended f32 atomics
    bucket_count<<<M_TOK / 256, 256, 0, stream>>>(input_ids, freq_i);
    bucket_fill<<<M_TOK / 256, 256, 0, stream>>>(input_ids, cursor, bucket);
    avg_from_buckets<<<NV, 128, 0, stream>>>(z, bucket, freq_i, out + OFF_AVG);

    // cluster assignment
    cn_norm<<<NK, 64, 0, stream>>>(centers, cn);
    argmax_kernel<<<NV, 128, 0, stream>>>(out + OFF_AVG, cn, cids, out + OFF_CID);

    // co-occurrence matrix
    build_masks<<<NV / 256, 256, 0, stream>>>(bow, masks, cntv);
    co_kernel<<<dim3(NV / 256, NV / 64), 256, 0, stream>>>(masks, cntv, out + OFF_CO);

    // online center update (closed form)
    cluster_scan<<<NK, 128, 0, stream>>>(out + OFF_AVG, cids, freq_i, vocab_w,
                                         centers, counts, out + OFF_NC);
}